// Round 16
// baseline (103.903 us; speedup 1.0000x reference)
//
#include <hip/hip_runtime.h>
#include <hip/hip_bf16.h>
#include <math.h>

#define B_SZ 2
#define S_SZ 2048
#define D_SZ 1024
#define H_SZ 16
#define HD_SZ 64
constexpr int M_ROWS = B_SZ * S_SZ;  // 4096

typedef __bf16 bf16x8 __attribute__((ext_vector_type(8)));
typedef __bf16 bf16x4 __attribute__((ext_vector_type(4)));
typedef float f32x4 __attribute__((ext_vector_type(4)));

#define GLOAD_LDS16(gsrc, ldst)                                              \
  __builtin_amdgcn_global_load_lds(                                          \
      (const __attribute__((address_space(1))) void*)(gsrc),                 \
      (__attribute__((address_space(3))) void*)(ldst), 16, 0, 0)

// ---------------------------------------------------------------------------
// Prep (one launch): z=0..3: W [K][N] fp32 -> Wt [N][K] bf16 transpose;
//                    z=4: X fp32 -> bf16 (16 elems/thread)
// ---------------------------------------------------------------------------
__global__ __launch_bounds__(256) void prep_all(const float* __restrict__ X,
                                                const float* __restrict__ W0,
                                                const float* __restrict__ W1,
                                                const float* __restrict__ W2,
                                                const float* __restrict__ W3,
                                                __bf16* __restrict__ Xb,
                                                __bf16* __restrict__ Wt) {
  __shared__ float Ts[32][33];
  const int z = blockIdx.z;
  if (z < 4) {
    const float* W = z == 0 ? W0 : (z == 1 ? W1 : (z == 2 ? W2 : W3));
    __bf16* out = Wt + (size_t)z * 1024 * 1024;
    const int k0 = blockIdx.x * 32, n0 = blockIdx.y * 32;
    const int tr = threadIdx.x >> 3;
    const int tc = (threadIdx.x & 7) * 4;
    const float4 v =
        *reinterpret_cast<const float4*>(&W[(size_t)(k0 + tr) * 1024 + n0 + tc]);
    Ts[tr][tc + 0] = v.x;
    Ts[tr][tc + 1] = v.y;
    Ts[tr][tc + 2] = v.z;
    Ts[tr][tc + 3] = v.w;
    __syncthreads();
    bf16x4 o;
#pragma unroll
    for (int j = 0; j < 4; ++j) o[j] = (__bf16)Ts[tc + j][tr];
    *reinterpret_cast<bf16x4*>(&out[(size_t)(n0 + tr) * 1024 + k0 + tc]) = o;
  } else {
    const int flat = blockIdx.y * 32 + blockIdx.x;
    const size_t e0 = ((size_t)flat * 256 + threadIdx.x) * 16;
#pragma unroll
    for (int half = 0; half < 2; ++half) {
      const float4 a = *reinterpret_cast<const float4*>(&X[e0 + half * 8]);
      const float4 b = *reinterpret_cast<const float4*>(&X[e0 + half * 8 + 4]);
      bf16x8 o;
      o[0] = (__bf16)a.x; o[1] = (__bf16)a.y; o[2] = (__bf16)a.z; o[3] = (__bf16)a.w;
      o[4] = (__bf16)b.x; o[5] = (__bf16)b.y; o[6] = (__bf16)b.z; o[7] = (__bf16)b.w;
      *reinterpret_cast<bf16x8*>(&Xb[e0 + half * 8]) = o;
    }
  }
}

// ---------------------------------------------------------------------------
// MFMA bf16 GEMM, 128xBN tile, BK=32, 4 waves (2x2). Double-buffered LDS,
// counted vmcnt (prefetch stays in flight across barriers).
// MODE 0: C0 fp32 [M][N] += bias0        (BN = 64)
// MODE 1: BN=128, N=3072. Q/K scattered to bf16 [B*H,S,64] via row-major
//         Ep staging; V written TRANSPOSED to Vt [B*H,64,S] via col-major
//         stride-40 Ep staging. Q scaled 0.125*log2(e).
// ---------------------------------------------------------------------------
template <int MODE, int BN>
__global__ __launch_bounds__(256) void gemm_mfma(
    const __bf16* __restrict__ Ab, const __bf16* __restrict__ Bt,
    const float* __restrict__ bias0, const float* __restrict__ bias1,
    const float* __restrict__ bias2, float* __restrict__ C0,
    __bf16* __restrict__ Q0, __bf16* __restrict__ K0, __bf16* __restrict__ V0,
    int M, int N, int K) {
  constexpr int NJ = BN / 32;
  __shared__ __bf16 As[2][128 * 32];
  __shared__ __bf16 Bs[2][BN * 32];
  __shared__ __bf16 Ep[(MODE == 1) ? 128 * 40 : 4];  // >= 32*132 too

  const int tid = threadIdx.x;
  const int lane = tid & 63;
  const int w = tid >> 6;
  const int lr = lane & 15, lg = lane >> 4;
  const int wr = w >> 1, wc = w & 1;
  const int bm = blockIdx.x * 128;
  const int bn = blockIdx.y * BN;

  const int r0 = tid >> 2, c0 = (tid & 3) * 8;
  const int r1 = (tid + 256) >> 2, c1 = ((tid + 256) & 3) * 8;
  const __bf16* aS0 = &Ab[(size_t)(bm + r0) * K + c0];
  const __bf16* aS1 = &Ab[(size_t)(bm + r1) * K + c1];
  const __bf16* bS0 = &Bt[(size_t)(bn + r0) * K + c0];
  const __bf16* bS1 = &Bt[(size_t)(bn + r1) * K + c1];

  f32x4 acc[4][NJ] = {};

  auto STAGE = [&](int buf) {
    GLOAD_LDS16(aS0, &As[buf][w * 512]);
    GLOAD_LDS16(aS1, &As[buf][2048 + w * 512]);
    GLOAD_LDS16(bS0, &Bs[buf][w * 512]);
    if constexpr (BN == 128) GLOAD_LDS16(bS1, &Bs[buf][2048 + w * 512]);
    aS0 += 32; aS1 += 32; bS0 += 32;
    if constexpr (BN == 128) bS1 += 32;
  };

  STAGE(0);
  asm volatile("s_waitcnt vmcnt(0)" ::: "memory");
  __builtin_amdgcn_s_barrier();
  __builtin_amdgcn_sched_barrier(0);
  int cur = 0;

  for (int k0 = 0; k0 < K; k0 += 32) {
    const bool has_next = (k0 + 32 < K);
    if (has_next) STAGE(cur ^ 1);
    if (k0) {
      if (has_next) {
        if constexpr (BN == 128)
          asm volatile("s_waitcnt vmcnt(4)" ::: "memory");
        else
          asm volatile("s_waitcnt vmcnt(3)" ::: "memory");
      } else {
        asm volatile("s_waitcnt vmcnt(0)" ::: "memory");
      }
      __builtin_amdgcn_s_barrier();
      __builtin_amdgcn_sched_barrier(0);
    }

    bf16x8 af[4], bfr[NJ];
#pragma unroll
    for (int i = 0; i < 4; ++i)
      af[i] = *reinterpret_cast<const bf16x8*>(&As[cur][(wr * 64 + i * 16 + lr) * 32 + lg * 8]);
#pragma unroll
    for (int j = 0; j < NJ; ++j)
      bfr[j] = *reinterpret_cast<const bf16x8*>(&Bs[cur][(wc * (BN / 2) + j * 16 + lr) * 32 + lg * 8]);
    __builtin_amdgcn_s_setprio(1);
#pragma unroll
    for (int i = 0; i < 4; ++i)
#pragma unroll
      for (int j = 0; j < NJ; ++j)
        acc[i][j] = __builtin_amdgcn_mfma_f32_16x16x32_bf16(af[i], bfr[j], acc[i][j], 0, 0, 0);
    __builtin_amdgcn_s_setprio(0);
    __builtin_amdgcn_sched_barrier(0);
    __builtin_amdgcn_s_barrier();
    cur ^= 1;
  }

  if (MODE == 0) {
#pragma unroll
    for (int j = 0; j < NJ; ++j) {
      const int n = bn + wc * (BN / 2) + j * 16 + lr;
      const float bs = bias0[n];
#pragma unroll
      for (int i = 0; i < 4; ++i) {
        const int mrow = bm + wr * 64 + i * 16 + lg * 4;
#pragma unroll
        for (int r = 0; r < 4; ++r)
          C0[(size_t)(mrow + r) * N + n] = acc[i][j][r] + bs;
      }
    }
  } else {
    const int which = bn >> 10;  // 0=Q, 1=K, 2=V
    const float* bp = which == 0 ? bias0 : (which == 1 ? bias1 : bias2);
    const float scale = which == 0 ? 0.18033688011112042f : 1.0f;  // 1/8*log2e
    float bias4[4];
#pragma unroll
    for (int j = 0; j < 4; ++j)
      bias4[j] = bp[(bn & 1023) + wc * 64 + j * 16 + lr];

    if (which < 2) {
      __bf16* dst = which == 0 ? Q0 : K0;
#pragma unroll
      for (int i = 0; i < 4; ++i) {
        __syncthreads();
        // row-major slab (32 rows x 128 cols), stride 132 (conflict-free)
#pragma unroll
        for (int j = 0; j < 4; ++j) {
          const int colw = wc * 64 + j * 16 + lr;
#pragma unroll
          for (int r = 0; r < 4; ++r)
            Ep[(wr * 16 + lg * 4 + r) * 132 + colw] =
                (__bf16)((acc[i][j][r] + bias4[j]) * scale);
        }
        __syncthreads();
#pragma unroll
        for (int u = 0; u < 2; ++u) {
          const int c = tid + u * 256;
          const int er = c >> 4;
          const int off = (c & 15) * 8;
          const int m = bm + (er >> 4) * 64 + i * 16 + (er & 15);
          const int nn = (bn & 1023) + off;
          const int hh = nn >> 6, hd = nn & 63;
          const int bb = m >> 11, ss = m & (S_SZ - 1);
          *reinterpret_cast<bf16x8*>(
              &dst[(((size_t)(bb * H_SZ + hh)) * S_SZ + ss) * HD_SZ + hd]) =
              *reinterpret_cast<const bf16x8*>(&Ep[er * 132 + off]);
        }
      }
    } else {
      // V -> Vt[((bb*H+hh)*64+hd)*S + ss] directly, via col-major Ep (stride 40)
#pragma unroll
      for (int i = 0; i < 4; ++i) {
        __syncthreads();
#pragma unroll
        for (int j = 0; j < 4; ++j) {
          const int colw = wc * 64 + j * 16 + lr;
#pragma unroll
          for (int r = 0; r < 4; ++r)
            Ep[colw * 40 + wr * 16 + lg * 4 + r] =
                (__bf16)(acc[i][j][r] + bias4[j]);
        }
        __syncthreads();
        const int col = tid & 127, r2 = tid >> 7;
        const int nn = (bn & 1023) + col;  // GLOBAL column
        const int hh = nn >> 6, hd = nn & 63;
        const int m0 = bm + r2 * 64 + i * 16;
        const int bb = m0 >> 11, ss0 = m0 & (S_SZ - 1);
        __bf16* dstp =
            &V0[(((size_t)(bb * H_SZ + hh)) * HD_SZ + hd) * S_SZ + ss0];
        *reinterpret_cast<bf16x8*>(dstp) =
            *reinterpret_cast<const bf16x8*>(&Ep[col * 40 + r2 * 16]);
        *reinterpret_cast<bf16x8*>(dstp + 8) =
            *reinterpret_cast<const bf16x8*>(&Ep[col * 40 + r2 * 16 + 8]);
      }
    }
  }
}

// ---------------------------------------------------------------------------
// MFMA bf16 causal flash attention, v13 = v12 + 32-col Ps half-buffer.
// Ps shrunk 64->32 key-cols (PST=36: b64 writes 4 accesses/bank, b128 reads
// 8/bank -- both at the LDS-minimum, conflict-free). PV consumes P in two
// kh-halves through the same per-wave buffer; per-wave in-order LDS ops make
// the half-swap sync-free (lgkmcnt only, no barrier). LDS 42.5->37.4KB ->
// 4 blocks/CU = 16 waves/CU (grid 1024 = exactly 4x256, statically balanced:
// each CU's four qb values sum to 62).
// Swapped QK^T (P row=key, col=q) -> packed cvt_pk + b64 P-stores.
// One {vmcnt(0); s_barrier} per tile; shift-free base-2 softmax; l via
// ones-MFMA; XOR-swizzled K/Vt staging; 2-pass vectorized epilogue.
// ---------------------------------------------------------------------------
__global__ __launch_bounds__(256) void attn_mfma(const __bf16* __restrict__ Q,
                                                 const __bf16* __restrict__ Kg,
                                                 const __bf16* __restrict__ Vtg,
                                                 __bf16* __restrict__ Aout) {
  constexpr int PST = 36;
  __shared__ __bf16 Ks[2][64 * 64];
  __shared__ __bf16 Vts[2][64 * 64];
  __shared__ __bf16 Ps[4][16 * PST];

  const int tid = threadIdx.x;
  const int lane = tid & 63;
  const int w = tid >> 6;
  const int lr = lane & 15;
  const int lg = lane >> 4;

  const int flat = blockIdx.x;
  const int g = flat >> 5;
  const int qb = (g < 16) ? (31 - g) : (g - 16);  // heavy-first LPT
  const int hb = flat & 31;
  const int h = hb >> 1, b = hb & 1;
  const size_t base = (size_t)(b * H_SZ + h) * S_SZ * HD_SZ;
  const int q0 = qb * 64 + w * 16;

  // Q fragments (pre-scaled by log2e/8); used as the B operand after swap
  bf16x8 aq[2];
#pragma unroll
  for (int hh = 0; hh < 2; ++hh)
    aq[hh] = *reinterpret_cast<const bf16x8*>(
        &Q[base + (size_t)(q0 + lr) * 64 + hh * 32 + lg * 8]);

  const int srow = lane >> 3;
  const int schunk = (lane & 7) ^ srow;

  bf16x8 ones8;
#pragma unroll
  for (int j = 0; j < 8; ++j) ones8[j] = (__bf16)1.0f;

  f32x4 oacc[4] = {};
  f32x4 oacc_l = {};

  const int ntiles = qb + 1;

  const int rbA = w * 16, rbB = w * 16 + 8;
  const __bf16* kS0 = &Kg[base + (size_t)(rbA + srow) * 64 + schunk * 8];
  const __bf16* kS1 = &Kg[base + (size_t)(rbB + srow) * 64 + schunk * 8];
  const __bf16* vS0 = &Vtg[base + (size_t)(rbA + srow) * S_SZ + schunk * 8];
  const __bf16* vS1 = &Vtg[base + (size_t)(rbB + srow) * S_SZ + schunk * 8];

  auto ISSUE = [&](int buf) {
    GLOAD_LDS16(kS0, &Ks[buf][rbA * 64]);
    GLOAD_LDS16(kS1, &Ks[buf][rbB * 64]);
    GLOAD_LDS16(vS0, &Vts[buf][rbA * 64]);
    GLOAD_LDS16(vS1, &Vts[buf][rbB * 64]);
  };

  ISSUE(0);
  int cur = 0;

  for (int t0 = 0; t0 < ntiles; ++t0) {
    // single sync point: own tile-t loads landed + all waves done with t-1
    asm volatile("s_waitcnt vmcnt(0)" ::: "memory");
    __builtin_amdgcn_s_barrier();
    __builtin_amdgcn_sched_barrier(0);

    // issue t+1 into the buffer t-1 used
    if (t0 + 1 < ntiles) {
      kS0 += 64 * 64; kS1 += 64 * 64;
      vS0 += 64;      vS1 += 64;
      ISSUE(cur ^ 1);
    }

    // ---- S^T = K Q^T : lane (lg,lr) -> q-row lr, keys t*16+lg*4+r ----
    f32x4 s[4];
    __builtin_amdgcn_s_setprio(1);
#pragma unroll
    for (int t = 0; t < 4; ++t) {
      const int row = t * 16 + lr;
      const bf16x8 k0f = *reinterpret_cast<const bf16x8*>(
          &Ks[cur][row * 64 + ((lg ^ (lr & 7)) * 8)]);
      const bf16x8 k1f = *reinterpret_cast<const bf16x8*>(
          &Ks[cur][row * 64 + (((4 | lg) ^ (lr & 7)) * 8)]);
      f32x4 z = (f32x4){0.f, 0.f, 0.f, 0.f};
      z = __builtin_amdgcn_mfma_f32_16x16x32_bf16(k0f, aq[0], z, 0, 0, 0);
      z = __builtin_amdgcn_mfma_f32_16x16x32_bf16(k1f, aq[1], z, 0, 0, 0);
      s[t] = z;
    }
    __builtin_amdgcn_s_setprio(0);

    // causal mask (transposed indices): key=t0*64+t*16+lg*4+r, qrow=q0+lr
    if (t0 == qb) {
      const int qrow = q0 + lr;
#pragma unroll
      for (int t = 0; t < 4; ++t) {
#pragma unroll
        for (int r = 0; r < 4; ++r) {
          const int key = t0 * 64 + t * 16 + lg * 4 + r;
          if (key > qrow) s[t][r] = -INFINITY;
        }
      }
    }

    // ---- P = exp2(S), packed to bf16 pairs ----
    unsigned int pk[4][2];
#pragma unroll
    for (int t = 0; t < 4; ++t) {
      float e0 = __builtin_amdgcn_exp2f(s[t][0]);
      float e1 = __builtin_amdgcn_exp2f(s[t][1]);
      float e2 = __builtin_amdgcn_exp2f(s[t][2]);
      float e3 = __builtin_amdgcn_exp2f(s[t][3]);
      asm("v_cvt_pk_bf16_f32 %0, %1, %2" : "=v"(pk[t][0]) : "v"(e0), "v"(e1));
      asm("v_cvt_pk_bf16_f32 %0, %1, %2" : "=v"(pk[t][1]) : "v"(e2), "v"(e3));
    }

    // ---- PV in two 32-key halves through the per-wave Ps buffer ----
    __builtin_amdgcn_s_setprio(1);
#pragma unroll
    for (int kh = 0; kh < 2; ++kh) {
#pragma unroll
      for (int t2 = 0; t2 < 2; ++t2) {
        uint2 q2;
        q2.x = pk[kh * 2 + t2][0];
        q2.y = pk[kh * 2 + t2][1];
        *reinterpret_cast<uint2*>(&Ps[w][lr * PST + t2 * 16 + lg * 4]) = q2;
      }
      asm volatile("s_waitcnt lgkmcnt(0)" ::: "memory");
      __builtin_amdgcn_sched_barrier(0);
      const bf16x8 pa =
          *reinterpret_cast<const bf16x8*>(&Ps[w][lr * PST + lg * 8]);
#pragma unroll
      for (int dc = 0; dc < 4; ++dc) {
        const int row = dc * 16 + lr;
        const bf16x8 vf = *reinterpret_cast<const bf16x8*>(
            &Vts[cur][row * 64 + (((kh * 4 + lg) ^ (lr & 7)) * 8)]);
        oacc[dc] = __builtin_amdgcn_mfma_f32_16x16x32_bf16(pa, vf, oacc[dc], 0, 0, 0);
      }
      oacc_l = __builtin_amdgcn_mfma_f32_16x16x32_bf16(pa, ones8, oacc_l, 0, 0, 0);
      __builtin_amdgcn_sched_barrier(0);
    }
    __builtin_amdgcn_s_setprio(0);
    __builtin_amdgcn_sched_barrier(0);
    cur ^= 1;
  }

  // ---- epilogue: O/l through Ps in two 32-col passes -> bf16x8 stores ----
  float inv[4];
#pragma unroll
  for (int r = 0; r < 4; ++r) inv[r] = 1.f / oacc_l[r];
  const int erow = lane >> 2;       // 0..15
  const int eoff = (lane & 3) * 8;  // 0,8,16,24
#pragma unroll
  for (int u = 0; u < 2; ++u) {
#pragma unroll
    for (int v = 0; v < 2; ++v) {
      const int dc = 2 * u + v;
#pragma unroll
      for (int r = 0; r < 4; ++r)
        Ps[w][(lg * 4 + r) * PST + v * 16 + lr] =
            (__bf16)(oacc[dc][r] * inv[r]);
    }
    asm volatile("s_waitcnt lgkmcnt(0)" ::: "memory");
    __builtin_amdgcn_sched_barrier(0);
    *reinterpret_cast<bf16x8*>(
        &Aout[(size_t)(b * S_SZ + q0 + erow) * D_SZ + h * 64 + u * 32 + eoff]) =
        *reinterpret_cast<const bf16x8*>(&Ps[w][erow * PST + eoff]);
    __builtin_amdgcn_sched_barrier(0);
  }
}

// ---------------------------------------------------------------------------
// Launch
// ---------------------------------------------------------------------------
extern "C" void kernel_launch(void* const* d_in, const int* in_sizes, int n_in,
                              void* d_out, int out_size, void* d_ws,
                              size_t ws_size, hipStream_t stream) {
  const float* X = (const float*)d_in[0];
  const float* Wq = (const float*)d_in[1];
  const float* bq = (const float*)d_in[2];
  const float* Wk = (const float*)d_in[3];
  const float* bk = (const float*)d_in[4];
  const float* Wv = (const float*)d_in[5];
  const float* bv = (const float*)d_in[6];
  const float* Wo = (const float*)d_in[7];
  const float* bo = (const float*)d_in[8];
  float* out = (float*)d_out;

  const size_t elems = (size_t)M_ROWS * D_SZ;  // 4 Mi
  const size_t welems = (size_t)D_SZ * D_SZ;   // 1 Mi
  __bf16* Xb = (__bf16*)d_ws;
  __bf16* Wt = Xb + elems;  // [4][1024][1024]: q,k,v,o transposed
  __bf16* Q = Wt + 4 * welems;
  __bf16* K = Q + elems;
  __bf16* Vt = K + elems;   // [B*H][64][S], written directly by QKV GEMM
  __bf16* Ahb = Vt + elems;

  prep_all<<<dim3(32, 32, 5), 256, 0, stream>>>(X, Wq, Wk, Wv, Wo, Xb, Wt);

  gemm_mfma<1, 128><<<dim3(M_ROWS / 128, 3072 / 128), 256, 0, stream>>>(
      Xb, Wt, bq, bk, bv, nullptr, Q, K, Vt, M_ROWS, 3072, D_SZ);

  attn_mfma<<<dim3(1024), 256, 0, stream>>>(Q, K, Vt, Ahb);

  gemm_mfma<0, 64><<<dim3(M_ROWS / 128, D_SZ / 64), 256, 0, stream>>>(
      Ahb, Wt + 3 * welems, bo, nullptr, nullptr, out, nullptr, nullptr,
      nullptr, M_ROWS, D_SZ, D_SZ);
}

// Round 17
// 102.798 us; speedup vs baseline: 1.0107x; 1.0107x over previous
//
#include <hip/hip_runtime.h>
#include <hip/hip_bf16.h>
#include <math.h>

#define B_SZ 2
#define S_SZ 2048
#define D_SZ 1024
#define H_SZ 16
#define HD_SZ 64
constexpr int M_ROWS = B_SZ * S_SZ;  // 4096

typedef __bf16 bf16x8 __attribute__((ext_vector_type(8)));
typedef __bf16 bf16x4 __attribute__((ext_vector_type(4)));
typedef float f32x4 __attribute__((ext_vector_type(4)));

#define GLOAD_LDS16(gsrc, ldst)                                              \
  __builtin_amdgcn_global_load_lds(                                          \
      (const __attribute__((address_space(1))) void*)(gsrc),                 \
      (__attribute__((address_space(3))) void*)(ldst), 16, 0, 0)

// ---------------------------------------------------------------------------
// Prep (one launch): z=0..3: W [K][N] fp32 -> Wt [N][K] bf16 transpose;
//                    z=4: X fp32 -> bf16 (16 elems/thread)
// ---------------------------------------------------------------------------
__global__ __launch_bounds__(256) void prep_all(const float* __restrict__ X,
                                                const float* __restrict__ W0,
                                                const float* __restrict__ W1,
                                                const float* __restrict__ W2,
                                                const float* __restrict__ W3,
                                                __bf16* __restrict__ Xb,
                                                __bf16* __restrict__ Wt) {
  __shared__ float Ts[32][33];
  const int z = blockIdx.z;
  if (z < 4) {
    const float* W = z == 0 ? W0 : (z == 1 ? W1 : (z == 2 ? W2 : W3));
    __bf16* out = Wt + (size_t)z * 1024 * 1024;
    const int k0 = blockIdx.x * 32, n0 = blockIdx.y * 32;
    const int tr = threadIdx.x >> 3;
    const int tc = (threadIdx.x & 7) * 4;
    const float4 v =
        *reinterpret_cast<const float4*>(&W[(size_t)(k0 + tr) * 1024 + n0 + tc]);
    Ts[tr][tc + 0] = v.x;
    Ts[tr][tc + 1] = v.y;
    Ts[tr][tc + 2] = v.z;
    Ts[tr][tc + 3] = v.w;
    __syncthreads();
    bf16x4 o;
#pragma unroll
    for (int j = 0; j < 4; ++j) o[j] = (__bf16)Ts[tc + j][tr];
    *reinterpret_cast<bf16x4*>(&out[(size_t)(n0 + tr) * 1024 + k0 + tc]) = o;
  } else {
    const int flat = blockIdx.y * 32 + blockIdx.x;
    const size_t e0 = ((size_t)flat * 256 + threadIdx.x) * 16;
#pragma unroll
    for (int half = 0; half < 2; ++half) {
      const float4 a = *reinterpret_cast<const float4*>(&X[e0 + half * 8]);
      const float4 b = *reinterpret_cast<const float4*>(&X[e0 + half * 8 + 4]);
      bf16x8 o;
      o[0] = (__bf16)a.x; o[1] = (__bf16)a.y; o[2] = (__bf16)a.z; o[3] = (__bf16)a.w;
      o[4] = (__bf16)b.x; o[5] = (__bf16)b.y; o[6] = (__bf16)b.z; o[7] = (__bf16)b.w;
      *reinterpret_cast<bf16x8*>(&Xb[e0 + half * 8]) = o;
    }
  }
}

// ---------------------------------------------------------------------------
// MFMA bf16 GEMM, 128xBN tile, BK=32, 4 waves (2x2). Double-buffered LDS,
// counted vmcnt (prefetch stays in flight across barriers).
// MODE 0: C0 fp32 [M][N] += bias0, vectorized float4 epilogue via Ep (BN=64)
// MODE 1: BN=128, N=3072. Q/K scattered to bf16 [B*H,S,64] via row-major
//         Ep staging; V written TRANSPOSED to Vt [B*H,64,S] via col-major
//         stride-40 Ep staging. Q scaled 0.125*log2(e).
// ---------------------------------------------------------------------------
template <int MODE, int BN>
__global__ __launch_bounds__(256) void gemm_mfma(
    const __bf16* __restrict__ Ab, const __bf16* __restrict__ Bt,
    const float* __restrict__ bias0, const float* __restrict__ bias1,
    const float* __restrict__ bias2, float* __restrict__ C0,
    __bf16* __restrict__ Q0, __bf16* __restrict__ K0, __bf16* __restrict__ V0,
    int M, int N, int K) {
  constexpr int NJ = BN / 32;
  __shared__ __bf16 As[2][128 * 32];
  __shared__ __bf16 Bs[2][BN * 32];
  __shared__ __bf16 Ep[128 * 40];  // MODE1: bf16 staging; MODE0: 32x68 fp32

  const int tid = threadIdx.x;
  const int lane = tid & 63;
  const int w = tid >> 6;
  const int lr = lane & 15, lg = lane >> 4;
  const int wr = w >> 1, wc = w & 1;
  const int bm = blockIdx.x * 128;
  const int bn = blockIdx.y * BN;

  const int r0 = tid >> 2, c0 = (tid & 3) * 8;
  const int r1 = (tid + 256) >> 2, c1 = ((tid + 256) & 3) * 8;
  const __bf16* aS0 = &Ab[(size_t)(bm + r0) * K + c0];
  const __bf16* aS1 = &Ab[(size_t)(bm + r1) * K + c1];
  const __bf16* bS0 = &Bt[(size_t)(bn + r0) * K + c0];
  const __bf16* bS1 = &Bt[(size_t)(bn + r1) * K + c1];

  f32x4 acc[4][NJ] = {};

  auto STAGE = [&](int buf) {
    GLOAD_LDS16(aS0, &As[buf][w * 512]);
    GLOAD_LDS16(aS1, &As[buf][2048 + w * 512]);
    GLOAD_LDS16(bS0, &Bs[buf][w * 512]);
    if constexpr (BN == 128) GLOAD_LDS16(bS1, &Bs[buf][2048 + w * 512]);
    aS0 += 32; aS1 += 32; bS0 += 32;
    if constexpr (BN == 128) bS1 += 32;
  };

  STAGE(0);
  asm volatile("s_waitcnt vmcnt(0)" ::: "memory");
  __builtin_amdgcn_s_barrier();
  __builtin_amdgcn_sched_barrier(0);
  int cur = 0;

  for (int k0 = 0; k0 < K; k0 += 32) {
    const bool has_next = (k0 + 32 < K);
    if (has_next) STAGE(cur ^ 1);
    if (k0) {
      if (has_next) {
        if constexpr (BN == 128)
          asm volatile("s_waitcnt vmcnt(4)" ::: "memory");
        else
          asm volatile("s_waitcnt vmcnt(3)" ::: "memory");
      } else {
        asm volatile("s_waitcnt vmcnt(0)" ::: "memory");
      }
      __builtin_amdgcn_s_barrier();
      __builtin_amdgcn_sched_barrier(0);
    }

    bf16x8 af[4], bfr[NJ];
#pragma unroll
    for (int i = 0; i < 4; ++i)
      af[i] = *reinterpret_cast<const bf16x8*>(&As[cur][(wr * 64 + i * 16 + lr) * 32 + lg * 8]);
#pragma unroll
    for (int j = 0; j < NJ; ++j)
      bfr[j] = *reinterpret_cast<const bf16x8*>(&Bs[cur][(wc * (BN / 2) + j * 16 + lr) * 32 + lg * 8]);
    __builtin_amdgcn_s_setprio(1);
#pragma unroll
    for (int i = 0; i < 4; ++i)
#pragma unroll
      for (int j = 0; j < NJ; ++j)
        acc[i][j] = __builtin_amdgcn_mfma_f32_16x16x32_bf16(af[i], bfr[j], acc[i][j], 0, 0, 0);
    __builtin_amdgcn_s_setprio(0);
    __builtin_amdgcn_sched_barrier(0);
    __builtin_amdgcn_s_barrier();
    cur ^= 1;
  }

  if (MODE == 0) {
    // vectorized fp32 epilogue: 32x64 slab -> Ep (stride 68 fp32) -> float4
    float* Epf = reinterpret_cast<float*>(&Ep[0]);
    float bias2r[2];
#pragma unroll
    for (int j = 0; j < 2; ++j)
      bias2r[j] = bias0[bn + wc * 32 + j * 16 + lr];
#pragma unroll
    for (int i = 0; i < 4; ++i) {
      __syncthreads();
#pragma unroll
      for (int j = 0; j < NJ; ++j) {
        const int colw = wc * 32 + j * 16 + lr;
#pragma unroll
        for (int r = 0; r < 4; ++r)
          Epf[(wr * 16 + lg * 4 + r) * 68 + colw] = acc[i][j][r] + bias2r[j];
      }
      __syncthreads();
#pragma unroll
      for (int u = 0; u < 2; ++u) {
        const int c = tid + u * 256;      // 0..511
        const int sr = c >> 4;            // 0..31
        const int off = (c & 15) * 4;     // 0..60
        const int m = bm + (sr >> 4) * 64 + i * 16 + (sr & 15);
        *reinterpret_cast<float4*>(&C0[(size_t)m * N + bn + off]) =
            *reinterpret_cast<const float4*>(&Epf[sr * 68 + off]);
      }
    }
  } else {
    const int which = bn >> 10;  // 0=Q, 1=K, 2=V
    const float* bp = which == 0 ? bias0 : (which == 1 ? bias1 : bias2);
    const float scale = which == 0 ? 0.18033688011112042f : 1.0f;  // 1/8*log2e
    float bias4[4];
#pragma unroll
    for (int j = 0; j < 4; ++j)
      bias4[j] = bp[(bn & 1023) + wc * 64 + j * 16 + lr];

    if (which < 2) {
      __bf16* dst = which == 0 ? Q0 : K0;
#pragma unroll
      for (int i = 0; i < 4; ++i) {
        __syncthreads();
        // row-major slab (32 rows x 128 cols), stride 132 (conflict-free)
#pragma unroll
        for (int j = 0; j < 4; ++j) {
          const int colw = wc * 64 + j * 16 + lr;
#pragma unroll
          for (int r = 0; r < 4; ++r)
            Ep[(wr * 16 + lg * 4 + r) * 132 + colw] =
                (__bf16)((acc[i][j][r] + bias4[j]) * scale);
        }
        __syncthreads();
#pragma unroll
        for (int u = 0; u < 2; ++u) {
          const int c = tid + u * 256;
          const int er = c >> 4;
          const int off = (c & 15) * 8;
          const int m = bm + (er >> 4) * 64 + i * 16 + (er & 15);
          const int nn = (bn & 1023) + off;
          const int hh = nn >> 6, hd = nn & 63;
          const int bb = m >> 11, ss = m & (S_SZ - 1);
          *reinterpret_cast<bf16x8*>(
              &dst[(((size_t)(bb * H_SZ + hh)) * S_SZ + ss) * HD_SZ + hd]) =
              *reinterpret_cast<const bf16x8*>(&Ep[er * 132 + off]);
        }
      }
    } else {
      // V -> Vt[((bb*H+hh)*64+hd)*S + ss] directly, via col-major Ep (stride 40)
#pragma unroll
      for (int i = 0; i < 4; ++i) {
        __syncthreads();
#pragma unroll
        for (int j = 0; j < 4; ++j) {
          const int colw = wc * 64 + j * 16 + lr;
#pragma unroll
          for (int r = 0; r < 4; ++r)
            Ep[colw * 40 + wr * 16 + lg * 4 + r] =
                (__bf16)(acc[i][j][r] + bias4[j]);
        }
        __syncthreads();
        const int col = tid & 127, r2 = tid >> 7;
        const int nn = (bn & 1023) + col;  // GLOBAL column
        const int hh = nn >> 6, hd = nn & 63;
        const int m0 = bm + r2 * 64 + i * 16;
        const int bb = m0 >> 11, ss0 = m0 & (S_SZ - 1);
        __bf16* dstp =
            &V0[(((size_t)(bb * H_SZ + hh)) * HD_SZ + hd) * S_SZ + ss0];
        *reinterpret_cast<bf16x8*>(dstp) =
            *reinterpret_cast<const bf16x8*>(&Ep[col * 40 + r2 * 16]);
        *reinterpret_cast<bf16x8*>(dstp + 8) =
            *reinterpret_cast<const bf16x8*>(&Ep[col * 40 + r2 * 16 + 8]);
      }
    }
  }
}

// ---------------------------------------------------------------------------
// MFMA bf16 causal flash attention, v12 (R15 config — best measured).
// Swapped QK^T (P row=key, col=q-row): packed cvt_pk + b64 P-stores.
// 4 waves x 16 q-rows; grid 1024 (4 blocks/CU); one {vmcnt(0); s_barrier}
// per tile; shift-free base-2 softmax; l via ones-MFMA; XOR-swizzled
// K/Vt staging; vectorized bf16x8 epilogue through Ps (PST=76).
// ---------------------------------------------------------------------------
__global__ __launch_bounds__(256) void attn_mfma(const __bf16* __restrict__ Q,
                                                 const __bf16* __restrict__ Kg,
                                                 const __bf16* __restrict__ Vtg,
                                                 __bf16* __restrict__ Aout) {
  constexpr int PST = 76;
  __shared__ __bf16 Ks[2][64 * 64];
  __shared__ __bf16 Vts[2][64 * 64];
  __shared__ __bf16 Ps[4][16 * PST];

  const int tid = threadIdx.x;
  const int lane = tid & 63;
  const int w = tid >> 6;
  const int lr = lane & 15;
  const int lg = lane >> 4;

  const int flat = blockIdx.x;
  const int g = flat >> 5;
  const int qb = (g < 16) ? (31 - g) : (g - 16);  // heavy-first LPT
  const int hb = flat & 31;
  const int h = hb >> 1, b = hb & 1;
  const size_t base = (size_t)(b * H_SZ + h) * S_SZ * HD_SZ;
  const int q0 = qb * 64 + w * 16;

  // Q fragments (pre-scaled by log2e/8); used as the B operand after swap
  bf16x8 aq[2];
#pragma unroll
  for (int hh = 0; hh < 2; ++hh)
    aq[hh] = *reinterpret_cast<const bf16x8*>(
        &Q[base + (size_t)(q0 + lr) * 64 + hh * 32 + lg * 8]);

  const int srow = lane >> 3;
  const int schunk = (lane & 7) ^ srow;

  bf16x8 ones8;
#pragma unroll
  for (int j = 0; j < 8; ++j) ones8[j] = (__bf16)1.0f;

  f32x4 oacc[4] = {};
  f32x4 oacc_l = {};

  const int ntiles = qb + 1;

  const int rbA = w * 16, rbB = w * 16 + 8;
  const __bf16* kS0 = &Kg[base + (size_t)(rbA + srow) * 64 + schunk * 8];
  const __bf16* kS1 = &Kg[base + (size_t)(rbB + srow) * 64 + schunk * 8];
  const __bf16* vS0 = &Vtg[base + (size_t)(rbA + srow) * S_SZ + schunk * 8];
  const __bf16* vS1 = &Vtg[base + (size_t)(rbB + srow) * S_SZ + schunk * 8];

  auto ISSUE = [&](int buf) {
    GLOAD_LDS16(kS0, &Ks[buf][rbA * 64]);
    GLOAD_LDS16(kS1, &Ks[buf][rbB * 64]);
    GLOAD_LDS16(vS0, &Vts[buf][rbA * 64]);
    GLOAD_LDS16(vS1, &Vts[buf][rbB * 64]);
  };

  ISSUE(0);
  int cur = 0;

  for (int t0 = 0; t0 < ntiles; ++t0) {
    // single sync point: own tile-t loads landed + all waves done with t-1
    asm volatile("s_waitcnt vmcnt(0)" ::: "memory");
    __builtin_amdgcn_s_barrier();
    __builtin_amdgcn_sched_barrier(0);

    // issue t+1 into the buffer t-1 used
    if (t0 + 1 < ntiles) {
      kS0 += 64 * 64; kS1 += 64 * 64;
      vS0 += 64;      vS1 += 64;
      ISSUE(cur ^ 1);
    }

    // ---- S^T = K Q^T : lane (lg,lr) -> q-row lr, keys t*16+lg*4+r ----
    f32x4 s[4];
    __builtin_amdgcn_s_setprio(1);
#pragma unroll
    for (int t = 0; t < 4; ++t) {
      const int row = t * 16 + lr;
      const bf16x8 k0f = *reinterpret_cast<const bf16x8*>(
          &Ks[cur][row * 64 + ((lg ^ (lr & 7)) * 8)]);
      const bf16x8 k1f = *reinterpret_cast<const bf16x8*>(
          &Ks[cur][row * 64 + (((4 | lg) ^ (lr & 7)) * 8)]);
      f32x4 z = (f32x4){0.f, 0.f, 0.f, 0.f};
      z = __builtin_amdgcn_mfma_f32_16x16x32_bf16(k0f, aq[0], z, 0, 0, 0);
      z = __builtin_amdgcn_mfma_f32_16x16x32_bf16(k1f, aq[1], z, 0, 0, 0);
      s[t] = z;
    }
    __builtin_amdgcn_s_setprio(0);

    // causal mask (transposed indices): key=t0*64+t*16+lg*4+r, qrow=q0+lr
    if (t0 == qb) {
      const int qrow = q0 + lr;
#pragma unroll
      for (int t = 0; t < 4; ++t) {
#pragma unroll
        for (int r = 0; r < 4; ++r) {
          const int key = t0 * 64 + t * 16 + lg * 4 + r;
          if (key > qrow) s[t][r] = -INFINITY;
        }
      }
    }

    // ---- P = exp2(S) -> packed b64 stores (4 consecutive keys/lane) ----
#pragma unroll
    for (int t = 0; t < 4; ++t) {
      float e0 = __builtin_amdgcn_exp2f(s[t][0]);
      float e1 = __builtin_amdgcn_exp2f(s[t][1]);
      float e2 = __builtin_amdgcn_exp2f(s[t][2]);
      float e3 = __builtin_amdgcn_exp2f(s[t][3]);
      unsigned int w0, w1;
      asm("v_cvt_pk_bf16_f32 %0, %1, %2" : "=v"(w0) : "v"(e0), "v"(e1));
      asm("v_cvt_pk_bf16_f32 %0, %1, %2" : "=v"(w1) : "v"(e2), "v"(e3));
      uint2 pk; pk.x = w0; pk.y = w1;
      *reinterpret_cast<uint2*>(&Ps[w][lr * PST + t * 16 + lg * 4]) = pk;
    }
    asm volatile("s_waitcnt lgkmcnt(0)" ::: "memory");
    __builtin_amdgcn_sched_barrier(0);

    // ---- O += P V ; l += P . 1 ----
    __builtin_amdgcn_s_setprio(1);
#pragma unroll
    for (int kh = 0; kh < 2; ++kh) {
      const bf16x8 pa = *reinterpret_cast<const bf16x8*>(
          &Ps[w][lr * PST + kh * 32 + lg * 8]);
#pragma unroll
      for (int dc = 0; dc < 4; ++dc) {
        const int row = dc * 16 + lr;
        const bf16x8 vf = *reinterpret_cast<const bf16x8*>(
            &Vts[cur][row * 64 + (((kh * 4 + lg) ^ (lr & 7)) * 8)]);
        oacc[dc] = __builtin_amdgcn_mfma_f32_16x16x32_bf16(pa, vf, oacc[dc], 0, 0, 0);
      }
      oacc_l = __builtin_amdgcn_mfma_f32_16x16x32_bf16(pa, ones8, oacc_l, 0, 0, 0);
    }
    __builtin_amdgcn_s_setprio(0);
    __builtin_amdgcn_sched_barrier(0);
    cur ^= 1;
  }

  // ---- epilogue: O/l -> per-wave Ps (conflict-free) -> bf16x8 stores ----
#pragma unroll
  for (int r = 0; r < 4; ++r) {
    const float inv = 1.f / oacc_l[r];
#pragma unroll
    for (int dc = 0; dc < 4; ++dc)
      Ps[w][(lg * 4 + r) * PST + dc * 16 + lr] = (__bf16)(oacc[dc][r] * inv);
  }
  asm volatile("s_waitcnt lgkmcnt(0)" ::: "memory");
  __builtin_amdgcn_sched_barrier(0);
#pragma unroll
  for (int u = 0; u < 2; ++u) {
    const int c = lane + u * 64;
    const int row = c >> 3;
    const int off = (c & 7) * 8;
    const int qg = q0 + row;
    *reinterpret_cast<bf16x8*>(
        &Aout[(size_t)(b * S_SZ + qg) * D_SZ + h * 64 + off]) =
        *reinterpret_cast<const bf16x8*>(&Ps[w][row * PST + off]);
  }
}

// ---------------------------------------------------------------------------
// Launch
// ---------------------------------------------------------------------------
extern "C" void kernel_launch(void* const* d_in, const int* in_sizes, int n_in,
                              void* d_out, int out_size, void* d_ws,
                              size_t ws_size, hipStream_t stream) {
  const float* X = (const float*)d_in[0];
  const float* Wq = (const float*)d_in[1];
  const float* bq = (const float*)d_in[2];
  const float* Wk = (const float*)d_in[3];
  const float* bk = (const float*)d_in[4];
  const float* Wv = (const float*)d_in[5];
  const float* bv = (const float*)d_in[6];
  const float* Wo = (const float*)d_in[7];
  const float* bo = (const float*)d_in[8];
  float* out = (float*)d_out;

  const size_t elems = (size_t)M_ROWS * D_SZ;  // 4 Mi
  const size_t welems = (size_t)D_SZ * D_SZ;   // 1 Mi
  __bf16* Xb = (__bf16*)d_ws;
  __bf16* Wt = Xb + elems;  // [4][1024][1024]: q,k,v,o transposed
  __bf16* Q = Wt + 4 * welems;
  __bf16* K = Q + elems;
  __bf16* Vt = K + elems;   // [B*H][64][S], written directly by QKV GEMM
  __bf16* Ahb = Vt + elems;

  prep_all<<<dim3(32, 32, 5), 256, 0, stream>>>(X, Wq, Wk, Wv, Wo, Xb, Wt);

  gemm_mfma<1, 128><<<dim3(M_ROWS / 128, 3072 / 128), 256, 0, stream>>>(
      Xb, Wt, bq, bk, bv, nullptr, Q, K, Vt, M_ROWS, 3072, D_SZ);

  attn_mfma<<<dim3(1024), 256, 0, stream>>>(Q, K, Vt, Ahb);

  gemm_mfma<0, 64><<<dim3(M_ROWS / 128, D_SZ / 64), 256, 0, stream>>>(
      Ahb, Wt + 3 * welems, bo, nullptr, nullptr, out, nullptr, nullptr,
      nullptr, M_ROWS, D_SZ, D_SZ);
}